// Round 8
// baseline (221.346 us; speedup 1.0000x reference)
//
#include <hip/hip_runtime.h>
#include <math.h>

typedef float    floatx4 __attribute__((ext_vector_type(4)));
typedef _Float16 half8   __attribute__((ext_vector_type(8)));
typedef _Float16 half4v  __attribute__((ext_vector_type(4)));
typedef _Float16 half2v  __attribute__((ext_vector_type(2)));
typedef __fp16   fp16x2  __attribute__((ext_vector_type(2)));

constexpr int B    = 2;
constexpr int S    = 2048;
constexpr int NH   = 16;
constexpr int HD   = 64;
constexpr int DIM  = 1024;
constexpr int INNER = 1024;
constexpr int QKVN = 3072;
constexpr int NTOK = 4096;
constexpr float EPS = 1e-5f;
constexpr float MAX_SCALE = 10.0f;
constexpr float SCALE_LOG2E = 0.125f * 1.4426950408889634f;

#define MFMA32(a, b, c) __builtin_amdgcn_mfma_f32_16x16x32_f16((a), (b), (c), 0, 0, 0)

__device__ __forceinline__ half2v pkrtz(float a, float b) {
  fp16x2 t = __builtin_amdgcn_cvt_pkrtz(a, b);
  return __builtin_bit_cast(half2v, t);
}
__device__ __forceinline__ half2v hmax2(half2v a, half2v b) {
  return __builtin_elementwise_max(a, b);
}

// Direct global->LDS DMA, 16 B per lane (attn staging only; all GEMM
// DMA-staging variants measured WORSE than reg-prefetch: R1 157, R2/3 158,
// R4 162, R6 159 vs R0 152 us non-attn. Do not re-introduce in GEMM.)
__device__ __forceinline__ void gl_lds16(const _Float16* g, _Float16* l) {
  __builtin_amdgcn_global_load_lds(
      (__attribute__((address_space(1))) void*)g,
      (__attribute__((address_space(3))) void*)l, 16, 0, 0);
}

// ---------------------------------------------------------------------------
// Fused prep: blockIdx [0,2048) fp32->fp16 convert of hs;
// [2048,2816) transpose w_qkv; [2816,3072) transpose w_out.
// ---------------------------------------------------------------------------
__device__ __forceinline__ void transpose_tile(const float* __restrict__ w,
                                               _Float16* __restrict__ wT,
                                               int K, int N, int k0, int n0,
                                               _Float16* T, int tid) {
#pragma unroll
  for (int i = 0; i < 4; ++i) {
    int id = tid + 256 * i;
    int r = id >> 4, c = id & 15;
    float4 v = *(const float4*)&w[(size_t)(k0 + r) * N + n0 + c * 4];
    half4v s; s[0] = (_Float16)v.x; s[1] = (_Float16)v.y;
    s[2] = (_Float16)v.z; s[3] = (_Float16)v.w;
    *(half4v*)&T[r * 72 + c * 4] = s;
  }
  __syncthreads();
#pragma unroll
  for (int i = 0; i < 2; ++i) {
    int id = tid + 256 * i;
    int n = id >> 3, cs = id & 7;
    half8 o;
#pragma unroll
    for (int jj = 0; jj < 8; ++jj) o[jj] = T[(cs * 8 + jj) * 72 + n];
    *(half8*)&wT[(size_t)(n0 + n) * K + k0 + cs * 8] = o;
  }
}

__global__ __launch_bounds__(256)
void prep_all(const float* __restrict__ hs, const float* __restrict__ w_qkv,
              const float* __restrict__ w_out, _Float16* __restrict__ hsb,
              _Float16* __restrict__ wqkvT, _Float16* __restrict__ woutT) {
  __shared__ _Float16 T[64 * 72];
  const int bx = blockIdx.x, tid = threadIdx.x;
  if (bx < 2048) {
    int id = bx * 256 + tid;
    const float4 a = ((const float4*)hs)[id * 2];
    const float4 b = ((const float4*)hs)[id * 2 + 1];
    half8 o;
    o[0] = (_Float16)a.x; o[1] = (_Float16)a.y; o[2] = (_Float16)a.z; o[3] = (_Float16)a.w;
    o[4] = (_Float16)b.x; o[5] = (_Float16)b.y; o[6] = (_Float16)b.z; o[7] = (_Float16)b.w;
    ((half8*)hsb)[id] = o;
  } else if (bx < 2816) {
    int id = bx - 2048;
    transpose_tile(w_qkv, wqkvT, DIM, QKVN, (id / 48) * 64, (id % 48) * 64, T, tid);
  } else {
    int id = bx - 2816;
    transpose_tile(w_out, woutT, INNER, DIM, (id / 16) * 64, (id % 16) * 64, T, tid);
  }
}

// ---------------------------------------------------------------------------
// fp16 MFMA GEMM with register-prefetch staging (R0 version, measured best).
// BN=128 for both call sites (BN=64 gemm2 tried in R7: neutral/worse).
// ---------------------------------------------------------------------------
template<int BN, bool OUT_F16, typename OutT>
__global__ __launch_bounds__(256)
void gemm_bt(const _Float16* __restrict__ A, const _Float16* __restrict__ BT,
             const float* __restrict__ bias, OutT* __restrict__ C, int N, int K) {
  constexpr int NJ = BN / 32;             // col-frags per wave
  __shared__ _Float16 As[128 * 56];
  __shared__ _Float16 Bs[BN * 56];
  const int tid = threadIdx.x;
  const int wave = tid >> 6, lane = tid & 63, quad = lane >> 4, l16 = lane & 15;
  const int wm = wave >> 1, wn = wave & 1;
  const int m0 = blockIdx.y * 128, n0 = blockIdx.x * BN;

  const int id0 = tid, id1 = tid + 256;
  const int m_0 = id0 >> 2, c_0 = (id0 & 3) * 8;
  const int m_1 = id1 >> 2, c_1 = (id1 & 3) * 8;
  const _Float16* Ap0 = A + (size_t)(m0 + m_0) * K + c_0;
  const _Float16* Ap1 = A + (size_t)(m0 + m_1) * K + c_1;
  const _Float16* Bp0 = BT + (size_t)(n0 + m_0) * K + c_0;
  const _Float16* Bp1 = BT + (size_t)(n0 + m_1) * K + c_1;  // unused if BN=64

  half8 ar0 = *(const half8*)Ap0, ar1 = *(const half8*)Ap1;
  half8 br0 = *(const half8*)Bp0, br1;
  if constexpr (BN == 128) br1 = *(const half8*)Bp1;

  floatx4 acc[4][NJ] = {};

  for (int k0 = 0; k0 < K; k0 += 32) {
    __syncthreads();
    *(half8*)&As[m_0 * 56 + c_0] = ar0;
    *(half8*)&As[m_1 * 56 + c_1] = ar1;
    *(half8*)&Bs[m_0 * 56 + c_0] = br0;
    if constexpr (BN == 128) *(half8*)&Bs[m_1 * 56 + c_1] = br1;
    if (k0 + 32 < K) {
      ar0 = *(const half8*)(Ap0 + k0 + 32);
      ar1 = *(const half8*)(Ap1 + k0 + 32);
      br0 = *(const half8*)(Bp0 + k0 + 32);
      if constexpr (BN == 128) br1 = *(const half8*)(Bp1 + k0 + 32);
    }
    __syncthreads();
    half8 a[4], b[NJ];
#pragma unroll
    for (int i = 0; i < 4; ++i)
      a[i] = *(const half8*)&As[(wm * 64 + i * 16 + l16) * 56 + quad * 8];
#pragma unroll
    for (int j = 0; j < NJ; ++j)
      b[j] = *(const half8*)&Bs[(wn * (BN / 2) + j * 16 + l16) * 56 + quad * 8];
#pragma unroll
    for (int i = 0; i < 4; ++i)
#pragma unroll
      for (int j = 0; j < NJ; ++j)
        acc[i][j] = MFMA32(a[i], b[j], acc[i][j]);
  }

  const int rb = m0 + wm * 64 + quad * 4;
  const int cb = n0 + wn * (BN / 2) + l16;
#pragma unroll
  for (int j = 0; j < NJ; ++j) {
    const float bj = bias[cb + j * 16];
#pragma unroll
    for (int i = 0; i < 4; ++i) {
#pragma unroll
      for (int r = 0; r < 4; ++r) {
        float v = acc[i][j][r] + bj;
        size_t idx = (size_t)(rb + i * 16 + r) * N + cb + j * 16;
        if constexpr (OUT_F16) C[idx] = (_Float16)v; else C[idx] = v;
      }
    }
  }
}

// ---------------------------------------------------------------------------
// Fused post: blockIdx [0,4096) = per-token RMSNorm+rotary+hist-scale;
// [4096,5120) = V transpose/swizzle tiles (fragment order for PV MFMAs).
// ---------------------------------------------------------------------------
__global__ __launch_bounds__(256)
void post_all(const _Float16* __restrict__ qkvh, const float* __restrict__ rot,
              const float* __restrict__ nqw, const float* __restrict__ nkw,
              const float* __restrict__ hks, const int* __restrict__ octx,
              _Float16* __restrict__ qo_, _Float16* __restrict__ ko_,
              _Float16* __restrict__ vt) {
  __shared__ __align__(16) char arena[64 * 72 * 2];
  const int tid = threadIdx.x;
  if (blockIdx.x < 4096) {
    float* red = (float*)arena;
    const int token = blockIdx.x;
    const int b = token >> 11, spos = token & (S - 1);
    const _Float16* qrow = qkvh + (size_t)token * QKVN;
    const _Float16* krow = qrow + INNER;
    const float* r = rot + (size_t)token * (2 * HD);

    const int e0 = tid * 4;
    half4v qs = *(const half4v*)(qrow + e0);
    half4v ks = *(const half4v*)(krow + e0);
    float q4[4], k4[4];
#pragma unroll
    for (int i = 0; i < 4; ++i) { q4[i] = (float)qs[i]; k4[i] = (float)ks[i]; }

    float sq = 0.f, sk = 0.f;
#pragma unroll
    for (int i = 0; i < 4; ++i) { sq += q4[i] * q4[i]; sk += k4[i] * k4[i]; }
#pragma unroll
    for (int msk = 1; msk < 64; msk <<= 1) {
      sq += __shfl_xor(sq, msk);
      sk += __shfl_xor(sk, msk);
    }
    const int wv = tid >> 6;
    if ((tid & 63) == 0) { red[wv] = sq; red[4 + wv] = sk; }
    __syncthreads();
    sq = red[0] + red[1] + red[2] + red[3];
    sk = red[4] + red[5] + red[6] + red[7];

    const float qinv = 1.0f / sqrtf(sq * (1.0f / INNER) + EPS);
    const float kinv = 1.0f / sqrtf(sk * (1.0f / INNER) + EPS);

#pragma unroll
    for (int i = 0; i < 4; ++i) {
      q4[i] = q4[i] * qinv * nqw[e0 + i];
      k4[i] = k4[i] * kinv * nkw[e0 + i];
    }

    const int h = e0 >> 6, d0 = e0 & (HD - 1);
    const float c0 = r[d0],     s0 = r[HD + d0 + 1];
    const float c1 = r[d0 + 2], s1 = r[HD + d0 + 3];

    float qo[4], ko[4];
    qo[0] = q4[0] * c0 - q4[1] * s0;
    qo[1] = q4[0] * s0 + q4[1] * c0;
    qo[2] = q4[2] * c1 - q4[3] * s1;
    qo[3] = q4[2] * s1 + q4[3] * c1;
    ko[0] = k4[0] * c0 - k4[1] * s0;
    ko[1] = k4[0] * s0 + k4[1] * c0;
    ko[2] = k4[2] * c1 - k4[3] * s1;
    ko[3] = k4[2] * s1 + k4[3] * c1;

    const int hist = S - octx[0];
    if (hist > 0 && spos < hist) {
      const float sig = 1.0f / (1.0f + expf(-hks[h]));
      const float sc = 1.0f + sig * (MAX_SCALE - 1.0f);
#pragma unroll
      for (int i = 0; i < 4; ++i) ko[i] *= sc;
    }

    half4v qo4, ko4;
#pragma unroll
    for (int i = 0; i < 4; ++i) {
      qo4[i] = (_Float16)(qo[i] * SCALE_LOG2E);
      ko4[i] = (_Float16)ko[i];
    }
    const size_t obase = ((size_t)(b * NH + h) * S + spos) * HD + d0;
    *(half4v*)(qo_ + obase) = qo4;
    *(half4v*)(ko_ + obase) = ko4;
  } else {
    _Float16* T = (_Float16*)arena;
    const int id = blockIdx.x - 4096;
    const int bh = id & 31, kt = id >> 5;
    const int b = bh >> 4, h = bh & 15;
    const int s0 = kt * 64;
#pragma unroll
    for (int i = 0; i < 2; ++i) {
      int id2 = tid + 256 * i;
      int s = id2 >> 3, c = id2 & 7;
      *(half8*)&T[s * 72 + c * 8] =
          *(const half8*)&qkvh[(size_t)(b * S + s0 + s) * QKVN + 2 * INNER + h * HD + c * 8];
    }
    __syncthreads();
    _Float16* orow = vt + ((size_t)bh * 32 + kt) * 64 * 64;
#pragma unroll
    for (int i = 0; i < 4; ++i) {
      int id2 = tid + 256 * i;
      int d = id2 >> 4, g = id2 & 15;
      int quad = g >> 2, jj = g & 3;
      half4v o;
#pragma unroll
      for (int k = 0; k < 4; ++k) o[k] = T[(jj * 16 + quad * 4 + k) * 72 + d];
      *(half4v*)&orow[d * 64 + g * 4] = o;
    }
  }
}

// ---------------------------------------------------------------------------
// MFMA flash attention, R8: latency-bound fix. 256 thr = 4 waves, 64-row Q
// tile, ONE 64-row K/V tile per barrier, double-buffered -> 32 KB LDS ->
// 4 blocks/CU (grid 1024 = exactly 4/CU, 16 waves/CU). Independent blocks
// drift in phase, so one block's serial softmax overlaps another's MFMA
// burst (R7 analysis: 28 of 50.8 us were dependency/sync stalls at 2
// lockstepped blocks/CU). Per-wave structure unchanged: DMA staging with
// XOR source swizzle, defer-max, ones-MFMA row-sum, PV via 16x16x32, T5
// setprio.
// ---------------------------------------------------------------------------
__global__ __launch_bounds__(256, 4)
void attn_mfma(const _Float16* __restrict__ qb, const _Float16* __restrict__ kb,
               const _Float16* __restrict__ vt, _Float16* __restrict__ attnb) {
  __shared__ _Float16 Kbuf[2][64 * 64];
  __shared__ _Float16 Vbuf[2][64 * 64];
  const int bh = blockIdx.x;
  const int b = bh >> 4, h = bh & 15;
  const int q0 = blockIdx.y * 64;
  const int tid = threadIdx.x;
  const int wave = tid >> 6, lane = tid & 63, quad = lane >> 4, l16 = lane & 15;
  const int rx = l16 & 7;

  const _Float16* qbh = qb + (size_t)bh * S * HD;
  const _Float16* kbh = kb + (size_t)bh * S * HD;
  const _Float16* vbh = vt + (size_t)bh * S * HD;

  half8 aq[2];
#pragma unroll
  for (int ks = 0; ks < 2; ++ks)
    aq[ks] = *(const half8*)&qbh[(size_t)(q0 + wave * 16 + l16) * HD + ks * 32 + quad * 8];

  // DMA staging: 4 waves x 2 gl_lds16 each cover one 64x64 tile (8 KB).
  // Wave w, load i: rows w*16 + i*8 + (lane>>3); dest chunk = lane&7;
  // source pre-swizzled chunk = (lane&7) ^ (row&7).
  const int sr0 = wave * 16 + (lane >> 3);
  const int sf0 = sr0 * 64 + (((lane & 7) ^ (sr0 & 7)) * 8);
  const int sr1 = sr0 + 8;
  const int sf1 = sr1 * 64 + (((lane & 7) ^ (sr1 & 7)) * 8);

  auto stage = [&](int t, int buf) {
    const _Float16* kt = kbh + (size_t)t * 4096;
    const _Float16* vp = vbh + (size_t)t * 4096;
    gl_lds16(kt + sf0, &Kbuf[buf][wave * 1024]);
    gl_lds16(kt + sf1, &Kbuf[buf][wave * 1024 + 512]);
    gl_lds16(vp + sf0, &Vbuf[buf][wave * 1024]);
    gl_lds16(vp + sf1, &Vbuf[buf][wave * 1024 + 512]);
  };

  stage(0, 0);
  __syncthreads();   // drains vmcnt(0): tile 0 resident

  floatx4 o16[4] = {};
  floatx4 lacc = {};                      // row-sums, same layout as o16 rows
  float mrow = -INFINITY;

  half8 ones8;
#pragma unroll
  for (int i = 0; i < 8; ++i) ones8[i] = (_Float16)1.f;

  auto compute_tile = [&](const _Float16* K0, const _Float16* V0) {
    floatx4 sc[4] = {};
    __builtin_amdgcn_s_setprio(1);
#pragma unroll
    for (int jj = 0; jj < 4; ++jj) {
#pragma unroll
      for (int ks = 0; ks < 2; ++ks) {
        const int co = (jj * 16 + l16) * 64 + (((ks * 4 + quad) ^ rx) * 8);
        half8 ak = *(const half8*)&K0[co];
        sc[jj] = MFMA32(ak, aq[ks], sc[jj]);
      }
    }
    __builtin_amdgcn_s_setprio(0);

    half2v ph[8];
#pragma unroll
    for (int jj = 0; jj < 4; ++jj) {
      ph[jj * 2]     = pkrtz(sc[jj][0], sc[jj][1]);
      ph[jj * 2 + 1] = pkrtz(sc[jj][2], sc[jj][3]);
    }
    half2v mx2 = hmax2(hmax2(hmax2(ph[0], ph[1]), hmax2(ph[2], ph[3])),
                       hmax2(hmax2(ph[4], ph[5]), hmax2(ph[6], ph[7])));
    int mi = __builtin_bit_cast(int, mx2);
    mx2 = hmax2(mx2, __builtin_bit_cast(half2v, __shfl_xor(mi, 16)));
    mi = __builtin_bit_cast(int, mx2);
    mx2 = hmax2(mx2, __builtin_bit_cast(half2v, __shfl_xor(mi, 32)));
    const float mxf = fmaxf((float)mx2[0], (float)mx2[1]);
    // defer-max: P bounded by 2^4=16, safe in f16 / f32 accum.
    const bool up = mxf > mrow + 4.0f;
    const float mn = up ? mxf : mrow;
    const float alpha = up ? exp2f(mrow - mn) : 1.0f;
    mrow = mn;

    const _Float16 mnh = (_Float16)mn;
    half2v mn2; mn2[0] = mnh; mn2[1] = mnh;
    half2v pe[8];
#pragma unroll
    for (int i = 0; i < 8; ++i)
      pe[i] = __builtin_elementwise_exp2(ph[i] - mn2);

    if (__ballot(up)) {
      float alr[4];
#pragma unroll
      for (int r = 0; r < 4; ++r) alr[r] = __shfl(alpha, quad * 4 + r);
#pragma unroll
      for (int jb = 0; jb < 4; ++jb)
#pragma unroll
        for (int r = 0; r < 4; ++r) o16[jb][r] *= alr[r];
#pragma unroll
      for (int r = 0; r < 4; ++r) lacc[r] *= alr[r];
    }

    // K=32 A-frags for PV: p[t] = [cols of block 2t | block 2t+1]
    half8 pA[2];
#pragma unroll
    for (int t = 0; t < 2; ++t) {
      half4v lo = __builtin_shufflevector(pe[4 * t],     pe[4 * t + 1], 0, 1, 2, 3);
      half4v hi = __builtin_shufflevector(pe[4 * t + 2], pe[4 * t + 3], 0, 1, 2, 3);
      pA[t] = __builtin_shufflevector(lo, hi, 0, 1, 2, 3, 4, 5, 6, 7);
    }

    __builtin_amdgcn_s_setprio(1);
    // row-sum on the MFMA pipe
    lacc = MFMA32(pA[0], ones8, lacc);
    lacc = MFMA32(pA[1], ones8, lacc);

    // O += P@V : 16x16x32 MFMAs, one 16B V read each
#pragma unroll
    for (int jb = 0; jb < 4; ++jb) {
      const int vrow = (jb * 16 + l16) * 64;
#pragma unroll
      for (int t = 0; t < 2; ++t) {
        half8 vA = *(const half8*)&V0[vrow + (((2 * quad + t) ^ rx) * 8)];
        o16[jb] = MFMA32(pA[t], vA, o16[jb]);
      }
    }
    __builtin_amdgcn_s_setprio(0);
  };

  int cur = 0;
  for (int t = 0; t < 32; ++t) {       // 32 single 64-row K/V tiles
    if (t + 1 < 32) stage(t + 1, cur ^ 1);   // DMA; flies under compute
    compute_tile(Kbuf[cur], Vbuf[cur]);
    __syncthreads();                         // drains vmcnt: next tile ready
    cur ^= 1;
  }

  float linv[4];
#pragma unroll
  for (int r = 0; r < 4; ++r) linv[r] = 1.0f / lacc[r];   // no shuffles needed
#pragma unroll
  for (int jb = 0; jb < 4; ++jb) {
#pragma unroll
    for (int r = 0; r < 4; ++r) {
      const int row = q0 + wave * 16 + quad * 4 + r;
      attnb[(size_t)(b * S + row) * INNER + h * HD + jb * 16 + l16] =
          (_Float16)(o16[jb][r] * linv[r]);
    }
  }
}

// ---------------------------------------------------------------------------
extern "C" void kernel_launch(void* const* d_in, const int* in_sizes, int n_in,
                              void* d_out, int out_size, void* d_ws, size_t ws_size,
                              hipStream_t stream) {
  const float* hs    = (const float*)d_in[0];
  const float* rot   = (const float*)d_in[1];
  const float* w_qkv = (const float*)d_in[2];
  const float* b_qkv = (const float*)d_in[3];
  const float* nqw   = (const float*)d_in[4];
  const float* nkw   = (const float*)d_in[5];
  const float* w_out = (const float*)d_in[6];
  const float* b_out = (const float*)d_in[7];
  const float* hks   = (const float*)d_in[8];
  const int*   octx  = (const int*)d_in[9];

  _Float16* hsb   = (_Float16*)d_ws;                 // 0-8 MiB (attnb aliases)
  _Float16* attnb = hsb;
  _Float16* wqkvT = hsb   + (size_t)NTOK * DIM;      // 8-14 MiB
  _Float16* woutT = wqkvT + (size_t)QKVN * DIM;      // 14-16 MiB
  _Float16* qkvh  = woutT + (size_t)DIM * INNER;     // 16-40 MiB
  _Float16* q_h   = qkvh  + (size_t)NTOK * QKVN;     // 40-48 MiB
  _Float16* k_h   = q_h   + (size_t)B * NH * S * HD; // 48-56 MiB
  _Float16* vT    = k_h   + (size_t)B * NH * S * HD; // 56-64 MiB

  prep_all<<<3072, 256, 0, stream>>>(hs, w_qkv, w_out, hsb, wqkvT, woutT);

  gemm_bt<128, true, _Float16><<<dim3(QKVN / 128, NTOK / 128), 256, 0, stream>>>(
      hsb, wqkvT, b_qkv, qkvh, QKVN, DIM);

  post_all<<<5120, 256, 0, stream>>>(qkvh, rot, nqw, nkw, hks, octx, q_h, k_h, vT);

  attn_mfma<<<dim3(B * NH, S / 64), 256, 0, stream>>>(q_h, k_h, vT, attnb);

  gemm_bt<128, false, float><<<dim3(DIM / 128, NTOK / 128), 256, 0, stream>>>(
      attnb, woutT, b_out, (float*)d_out, DIM, INNER);
}

// Round 9
// 204.128 us; speedup vs baseline: 1.0844x; 1.0844x over previous
//
#include <hip/hip_runtime.h>
#include <math.h>

typedef float    floatx4 __attribute__((ext_vector_type(4)));
typedef _Float16 half8   __attribute__((ext_vector_type(8)));
typedef _Float16 half4v  __attribute__((ext_vector_type(4)));
typedef _Float16 half2v  __attribute__((ext_vector_type(2)));
typedef __fp16   fp16x2  __attribute__((ext_vector_type(2)));

constexpr int B    = 2;
constexpr int S    = 2048;
constexpr int NH   = 16;
constexpr int HD   = 64;
constexpr int DIM  = 1024;
constexpr int INNER = 1024;
constexpr int QKVN = 3072;
constexpr int NTOK = 4096;
constexpr float EPS = 1e-5f;
constexpr float MAX_SCALE = 10.0f;
constexpr float SCALE_LOG2E = 0.125f * 1.4426950408889634f;

#define MFMA32(a, b, c) __builtin_amdgcn_mfma_f32_16x16x32_f16((a), (b), (c), 0, 0, 0)

__device__ __forceinline__ half2v pkrtz(float a, float b) {
  fp16x2 t = __builtin_amdgcn_cvt_pkrtz(a, b);
  return __builtin_bit_cast(half2v, t);
}
__device__ __forceinline__ half2v hmax2(half2v a, half2v b) {
  return __builtin_elementwise_max(a, b);
}

// Direct global->LDS DMA, 16 B per lane (attn staging only; all GEMM
// DMA-staging variants measured WORSE than reg-prefetch: R1 157, R2/3 158,
// R4 162, R6 159 vs R0 152 us non-attn. Do not re-introduce in GEMM.)
__device__ __forceinline__ void gl_lds16(const _Float16* g, _Float16* l) {
  __builtin_amdgcn_global_load_lds(
      (__attribute__((address_space(1))) void*)g,
      (__attribute__((address_space(3))) void*)l, 16, 0, 0);
}

// ---------------------------------------------------------------------------
// Fused prep: blockIdx [0,2048) fp32->fp16 convert of hs;
// [2048,2816) transpose w_qkv; [2816,3072) transpose w_out.
// ---------------------------------------------------------------------------
__device__ __forceinline__ void transpose_tile(const float* __restrict__ w,
                                               _Float16* __restrict__ wT,
                                               int K, int N, int k0, int n0,
                                               _Float16* T, int tid) {
#pragma unroll
  for (int i = 0; i < 4; ++i) {
    int id = tid + 256 * i;
    int r = id >> 4, c = id & 15;
    float4 v = *(const float4*)&w[(size_t)(k0 + r) * N + n0 + c * 4];
    half4v s; s[0] = (_Float16)v.x; s[1] = (_Float16)v.y;
    s[2] = (_Float16)v.z; s[3] = (_Float16)v.w;
    *(half4v*)&T[r * 72 + c * 4] = s;
  }
  __syncthreads();
#pragma unroll
  for (int i = 0; i < 2; ++i) {
    int id = tid + 256 * i;
    int n = id >> 3, cs = id & 7;
    half8 o;
#pragma unroll
    for (int jj = 0; jj < 8; ++jj) o[jj] = T[(cs * 8 + jj) * 72 + n];
    *(half8*)&wT[(size_t)(n0 + n) * K + k0 + cs * 8] = o;
  }
}

__global__ __launch_bounds__(256)
void prep_all(const float* __restrict__ hs, const float* __restrict__ w_qkv,
              const float* __restrict__ w_out, _Float16* __restrict__ hsb,
              _Float16* __restrict__ wqkvT, _Float16* __restrict__ woutT) {
  __shared__ _Float16 T[64 * 72];
  const int bx = blockIdx.x, tid = threadIdx.x;
  if (bx < 2048) {
    int id = bx * 256 + tid;
    const float4 a = ((const float4*)hs)[id * 2];
    const float4 b = ((const float4*)hs)[id * 2 + 1];
    half8 o;
    o[0] = (_Float16)a.x; o[1] = (_Float16)a.y; o[2] = (_Float16)a.z; o[3] = (_Float16)a.w;
    o[4] = (_Float16)b.x; o[5] = (_Float16)b.y; o[6] = (_Float16)b.z; o[7] = (_Float16)b.w;
    ((half8*)hsb)[id] = o;
  } else if (bx < 2816) {
    int id = bx - 2048;
    transpose_tile(w_qkv, wqkvT, DIM, QKVN, (id / 48) * 64, (id % 48) * 64, T, tid);
  } else {
    int id = bx - 2816;
    transpose_tile(w_out, woutT, INNER, DIM, (id / 16) * 64, (id % 16) * 64, T, tid);
  }
}

// ---------------------------------------------------------------------------
// fp16 MFMA GEMM, R9: reg-prefetch staging (measured-best mechanism) with
// BK=64 instead of 32: barrier count halves (32->16), each prefetch gets a
// 2x compute window (32 MFMAs) to hide L2/L3 latency. Pitch 72 keeps the
// free-2-way fragment-read bank profile (rows stride 144B -> 16 lanes hit
// 8 distinct bank quads, 2-way = free per m136). LDS 36 KB -> 3 blocks/CU.
// ---------------------------------------------------------------------------
template<int BN, bool OUT_F16, typename OutT>
__global__ __launch_bounds__(256)
void gemm_bt(const _Float16* __restrict__ A, const _Float16* __restrict__ BT,
             const float* __restrict__ bias, OutT* __restrict__ C, int N, int K) {
  constexpr int NJ  = BN / 32;            // col-frags per wave
  constexpr int NSB = BN / 32;            // B staging slots per thread
  __shared__ _Float16 As[128 * 72];
  __shared__ _Float16 Bs[BN * 72];
  const int tid = threadIdx.x;
  const int wave = tid >> 6, lane = tid & 63, quad = lane >> 4, l16 = lane & 15;
  const int wm = wave >> 1, wn = wave & 1;
  const int m0 = blockIdx.y * 128, n0 = blockIdx.x * BN;

  // staging: thread covers rows r0+32s, k-cols [c0, c0+8) of the 64-wide slice
  const int r0 = tid >> 3;                // 0..31
  const int c0 = (tid & 7) * 8;           // 0..56
  const _Float16* Ap = A  + (size_t)(m0 + r0) * K + c0;
  const _Float16* Bp = BT + (size_t)(n0 + r0) * K + c0;

  half8 ar[4], br[NSB];
#pragma unroll
  for (int s = 0; s < 4; ++s) ar[s] = *(const half8*)(Ap + (size_t)(32 * s) * K);
#pragma unroll
  for (int s = 0; s < NSB; ++s) br[s] = *(const half8*)(Bp + (size_t)(32 * s) * K);

  floatx4 acc[4][NJ] = {};

  for (int k0 = 0; k0 < K; k0 += 64) {
    __syncthreads();
#pragma unroll
    for (int s = 0; s < 4; ++s) *(half8*)&As[(r0 + 32 * s) * 72 + c0] = ar[s];
#pragma unroll
    for (int s = 0; s < NSB; ++s) *(half8*)&Bs[(r0 + 32 * s) * 72 + c0] = br[s];
    if (k0 + 64 < K) {
#pragma unroll
      for (int s = 0; s < 4; ++s)
        ar[s] = *(const half8*)(Ap + (size_t)(32 * s) * K + k0 + 64);
#pragma unroll
      for (int s = 0; s < NSB; ++s)
        br[s] = *(const half8*)(Bp + (size_t)(32 * s) * K + k0 + 64);
    }
    __syncthreads();
#pragma unroll
    for (int ks = 0; ks < 2; ++ks) {
      half8 a[4], b[NJ];
#pragma unroll
      for (int i = 0; i < 4; ++i)
        a[i] = *(const half8*)&As[(wm * 64 + i * 16 + l16) * 72 + ks * 32 + quad * 8];
#pragma unroll
      for (int j = 0; j < NJ; ++j)
        b[j] = *(const half8*)&Bs[(wn * (BN / 2) + j * 16 + l16) * 72 + ks * 32 + quad * 8];
#pragma unroll
      for (int i = 0; i < 4; ++i)
#pragma unroll
        for (int j = 0; j < NJ; ++j)
          acc[i][j] = MFMA32(a[i], b[j], acc[i][j]);
    }
  }

  const int rb = m0 + wm * 64 + quad * 4;
  const int cb = n0 + wn * (BN / 2) + l16;
#pragma unroll
  for (int j = 0; j < NJ; ++j) {
    const float bj = bias[cb + j * 16];
#pragma unroll
    for (int i = 0; i < 4; ++i) {
#pragma unroll
      for (int r = 0; r < 4; ++r) {
        float v = acc[i][j][r] + bj;
        size_t idx = (size_t)(rb + i * 16 + r) * N + cb + j * 16;
        if constexpr (OUT_F16) C[idx] = (_Float16)v; else C[idx] = v;
      }
    }
  }
}

// ---------------------------------------------------------------------------
// Fused post: blockIdx [0,4096) = per-token RMSNorm+rotary+hist-scale;
// [4096,5120) = V transpose/swizzle tiles (fragment order for PV MFMAs).
// ---------------------------------------------------------------------------
__global__ __launch_bounds__(256)
void post_all(const _Float16* __restrict__ qkvh, const float* __restrict__ rot,
              const float* __restrict__ nqw, const float* __restrict__ nkw,
              const float* __restrict__ hks, const int* __restrict__ octx,
              _Float16* __restrict__ qo_, _Float16* __restrict__ ko_,
              _Float16* __restrict__ vt) {
  __shared__ __align__(16) char arena[64 * 72 * 2];
  const int tid = threadIdx.x;
  if (blockIdx.x < 4096) {
    float* red = (float*)arena;
    const int token = blockIdx.x;
    const int b = token >> 11, spos = token & (S - 1);
    const _Float16* qrow = qkvh + (size_t)token * QKVN;
    const _Float16* krow = qrow + INNER;
    const float* r = rot + (size_t)token * (2 * HD);

    const int e0 = tid * 4;
    half4v qs = *(const half4v*)(qrow + e0);
    half4v ks = *(const half4v*)(krow + e0);
    float q4[4], k4[4];
#pragma unroll
    for (int i = 0; i < 4; ++i) { q4[i] = (float)qs[i]; k4[i] = (float)ks[i]; }

    float sq = 0.f, sk = 0.f;
#pragma unroll
    for (int i = 0; i < 4; ++i) { sq += q4[i] * q4[i]; sk += k4[i] * k4[i]; }
#pragma unroll
    for (int msk = 1; msk < 64; msk <<= 1) {
      sq += __shfl_xor(sq, msk);
      sk += __shfl_xor(sk, msk);
    }
    const int wv = tid >> 6;
    if ((tid & 63) == 0) { red[wv] = sq; red[4 + wv] = sk; }
    __syncthreads();
    sq = red[0] + red[1] + red[2] + red[3];
    sk = red[4] + red[5] + red[6] + red[7];

    const float qinv = 1.0f / sqrtf(sq * (1.0f / INNER) + EPS);
    const float kinv = 1.0f / sqrtf(sk * (1.0f / INNER) + EPS);

#pragma unroll
    for (int i = 0; i < 4; ++i) {
      q4[i] = q4[i] * qinv * nqw[e0 + i];
      k4[i] = k4[i] * kinv * nkw[e0 + i];
    }

    const int h = e0 >> 6, d0 = e0 & (HD - 1);
    const float c0 = r[d0],     s0 = r[HD + d0 + 1];
    const float c1 = r[d0 + 2], s1 = r[HD + d0 + 3];

    float qo[4], ko[4];
    qo[0] = q4[0] * c0 - q4[1] * s0;
    qo[1] = q4[0] * s0 + q4[1] * c0;
    qo[2] = q4[2] * c1 - q4[3] * s1;
    qo[3] = q4[2] * s1 + q4[3] * c1;
    ko[0] = k4[0] * c0 - k4[1] * s0;
    ko[1] = k4[0] * s0 + k4[1] * c0;
    ko[2] = k4[2] * c1 - k4[3] * s1;
    ko[3] = k4[2] * s1 + k4[3] * c1;

    const int hist = S - octx[0];
    if (hist > 0 && spos < hist) {
      const float sig = 1.0f / (1.0f + expf(-hks[h]));
      const float sc = 1.0f + sig * (MAX_SCALE - 1.0f);
#pragma unroll
      for (int i = 0; i < 4; ++i) ko[i] *= sc;
    }

    half4v qo4, ko4;
#pragma unroll
    for (int i = 0; i < 4; ++i) {
      qo4[i] = (_Float16)(qo[i] * SCALE_LOG2E);
      ko4[i] = (_Float16)ko[i];
    }
    const size_t obase = ((size_t)(b * NH + h) * S + spos) * HD + d0;
    *(half4v*)(qo_ + obase) = qo4;
    *(half4v*)(ko_ + obase) = ko4;
  } else {
    _Float16* T = (_Float16*)arena;
    const int id = blockIdx.x - 4096;
    const int bh = id & 31, kt = id >> 5;
    const int b = bh >> 4, h = bh & 15;
    const int s0 = kt * 64;
#pragma unroll
    for (int i = 0; i < 2; ++i) {
      int id2 = tid + 256 * i;
      int s = id2 >> 3, c = id2 & 7;
      *(half8*)&T[s * 72 + c * 8] =
          *(const half8*)&qkvh[(size_t)(b * S + s0 + s) * QKVN + 2 * INNER + h * HD + c * 8];
    }
    __syncthreads();
    _Float16* orow = vt + ((size_t)bh * 32 + kt) * 64 * 64;
#pragma unroll
    for (int i = 0; i < 4; ++i) {
      int id2 = tid + 256 * i;
      int d = id2 >> 4, g = id2 & 15;
      int quad = g >> 2, jj = g & 3;
      half4v o;
#pragma unroll
      for (int k = 0; k < 4; ++k) o[k] = T[(jj * 16 + quad * 4 + k) * 72 + d];
      *(half4v*)&orow[d * 64 + g * 4] = o;
    }
  }
}

// ---------------------------------------------------------------------------
// MFMA flash attention — R7 version verbatim (measured best: 50.8 us).
// 512 thr = 8 waves, 16 Q-rows/wave, 2 K-tiles per barrier with shared
// max-update, DMA staging with XOR source swizzle, defer-max, ones-MFMA
// row-sum, PV via 16x16x32, T5 setprio around MFMA clusters.
// (R8's 256-thr/single-tile variant regressed to 62 us — more blocks did
// not materialize as occupancy and per-tile serial overhead doubled.)
// ---------------------------------------------------------------------------
__global__ __launch_bounds__(512, 4)
void attn_mfma(const _Float16* __restrict__ qb, const _Float16* __restrict__ kb,
               const _Float16* __restrict__ vt, _Float16* __restrict__ attnb) {
  __shared__ _Float16 Kbuf[2][2][64 * 64];
  __shared__ _Float16 Vbuf[2][2][64 * 64];
  const int bh = blockIdx.x;
  const int b = bh >> 4, h = bh & 15;
  const int q0 = blockIdx.y * 128;
  const int tid = threadIdx.x;
  const int wave = tid >> 6, lane = tid & 63, quad = lane >> 4, l16 = lane & 15;
  const int rx = l16 & 7;

  const _Float16* qbh = qb + (size_t)bh * S * HD;
  const _Float16* kbh = kb + (size_t)bh * S * HD;
  const _Float16* vbh = vt + (size_t)bh * S * HD;

  half8 aq[2];
#pragma unroll
  for (int ks = 0; ks < 2; ++ks)
    aq[ks] = *(const half8*)&qbh[(size_t)(q0 + wave * 16 + l16) * HD + ks * 32 + quad * 8];

  const int srow = wave * 8 + (lane >> 3);
  const int soff = srow * 64 + (((lane & 7) ^ (srow & 7)) * 8);

  auto stage = [&](int p, int buf) {
    const _Float16* kt = kbh + (size_t)p * 8192;
    const _Float16* vp = vbh + (size_t)p * 8192;
    gl_lds16(kt + soff,        &Kbuf[buf][0][wave * 512]);
    gl_lds16(kt + 4096 + soff, &Kbuf[buf][1][wave * 512]);
    gl_lds16(vp + soff,        &Vbuf[buf][0][wave * 512]);
    gl_lds16(vp + 4096 + soff, &Vbuf[buf][1][wave * 512]);
  };

  stage(0, 0);
  __syncthreads();   // drains vmcnt(0): pair 0 resident

  floatx4 o16[4] = {};
  floatx4 lacc = {};                      // row-sums, same layout as o16 rows
  float mrow = -INFINITY;

  half8 ones8;
#pragma unroll
  for (int i = 0; i < 8; ++i) ones8[i] = (_Float16)1.f;

  auto compute_pair = [&](const _Float16* K0, const _Float16* K1,
                          const _Float16* V0, const _Float16* V1) {
    floatx4 scA[4] = {}, scB[4] = {};
    __builtin_amdgcn_s_setprio(1);
#pragma unroll
    for (int jj = 0; jj < 4; ++jj) {
#pragma unroll
      for (int ks = 0; ks < 2; ++ks) {
        const int co = (jj * 16 + l16) * 64 + (((ks * 4 + quad) ^ rx) * 8);
        half8 akA = *(const half8*)&K0[co];
        half8 akB = *(const half8*)&K1[co];
        scA[jj] = MFMA32(akA, aq[ks], scA[jj]);
        scB[jj] = MFMA32(akB, aq[ks], scB[jj]);
      }
    }
    __builtin_amdgcn_s_setprio(0);

    half2v phA[8], phB[8];
#pragma unroll
    for (int jj = 0; jj < 4; ++jj) {
      phA[jj * 2]     = pkrtz(scA[jj][0], scA[jj][1]);
      phA[jj * 2 + 1] = pkrtz(scA[jj][2], scA[jj][3]);
      phB[jj * 2]     = pkrtz(scB[jj][0], scB[jj][1]);
      phB[jj * 2 + 1] = pkrtz(scB[jj][2], scB[jj][3]);
    }
    half2v mA = hmax2(hmax2(hmax2(phA[0], phA[1]), hmax2(phA[2], phA[3])),
                      hmax2(hmax2(phA[4], phA[5]), hmax2(phA[6], phA[7])));
    half2v mB = hmax2(hmax2(hmax2(phB[0], phB[1]), hmax2(phB[2], phB[3])),
                      hmax2(hmax2(phB[4], phB[5]), hmax2(phB[6], phB[7])));
    half2v mx2 = hmax2(mA, mB);
    int mi = __builtin_bit_cast(int, mx2);
    mx2 = hmax2(mx2, __builtin_bit_cast(half2v, __shfl_xor(mi, 16)));
    mi = __builtin_bit_cast(int, mx2);
    mx2 = hmax2(mx2, __builtin_bit_cast(half2v, __shfl_xor(mi, 32)));
    const float mxf = fmaxf((float)mx2[0], (float)mx2[1]);
    const bool up = mxf > mrow + 4.0f;
    const float mn = up ? mxf : mrow;
    const float alpha = up ? exp2f(mrow - mn) : 1.0f;
    mrow = mn;

    const _Float16 mnh = (_Float16)mn;
    half2v mn2; mn2[0] = mnh; mn2[1] = mnh;
    half2v peA[8], peB[8];
#pragma unroll
    for (int i = 0; i < 8; ++i) {
      peA[i] = __builtin_elementwise_exp2(phA[i] - mn2);
      peB[i] = __builtin_elementwise_exp2(phB[i] - mn2);
    }

    if (__ballot(up)) {
      float alr[4];
#pragma unroll
      for (int r = 0; r < 4; ++r) alr[r] = __shfl(alpha, quad * 4 + r);
#pragma unroll
      for (int jb = 0; jb < 4; ++jb)
#pragma unroll
        for (int r = 0; r < 4; ++r) o16[jb][r] *= alr[r];
#pragma unroll
      for (int r = 0; r < 4; ++r) lacc[r] *= alr[r];
    }

    half8 pA[2], pB[2];
#pragma unroll
    for (int t = 0; t < 2; ++t) {
      half4v loA = __builtin_shufflevector(peA[4 * t],     peA[4 * t + 1], 0, 1, 2, 3);
      half4v hiA = __builtin_shufflevector(peA[4 * t + 2], peA[4 * t + 3], 0, 1, 2, 3);
      pA[t] = __builtin_shufflevector(loA, hiA, 0, 1, 2, 3, 4, 5, 6, 7);
      half4v loB = __builtin_shufflevector(peB[4 * t],     peB[4 * t + 1], 0, 1, 2, 3);
      half4v hiB = __builtin_shufflevector(peB[4 * t + 2], peB[4 * t + 3], 0, 1, 2, 3);
      pB[t] = __builtin_shufflevector(loB, hiB, 0, 1, 2, 3, 4, 5, 6, 7);
    }

    __builtin_amdgcn_s_setprio(1);
    lacc = MFMA32(pA[0], ones8, lacc);
    lacc = MFMA32(pA[1], ones8, lacc);
    lacc = MFMA32(pB[0], ones8, lacc);
    lacc = MFMA32(pB[1], ones8, lacc);

#pragma unroll
    for (int jb = 0; jb < 4; ++jb) {
      const int vrow = (jb * 16 + l16) * 64;
#pragma unroll
      for (int t = 0; t < 2; ++t) {
        half8 vA = *(const half8*)&V0[vrow + (((2 * quad + t) ^ rx) * 8)];
        half8 vB = *(const half8*)&V1[vrow + (((2 * quad + t) ^ rx) * 8)];
        o16[jb] = MFMA32(pA[t], vA, o16[jb]);
        o16[jb] = MFMA32(pB[t], vB, o16[jb]);
      }
    }
    __builtin_amdgcn_s_setprio(0);
  };

  int cur = 0;
  for (int p = 0; p < 16; ++p) {     // 16 pairs of 64-row K/V tiles
    if (p + 1 < 16) stage(p + 1, cur ^ 1);   // DMA; flies under compute
    compute_pair(Kbuf[cur][0], Kbuf[cur][1], Vbuf[cur][0], Vbuf[cur][1]);
    __syncthreads();                         // drains vmcnt: next pair ready
    cur ^= 1;
  }

  float linv[4];
#pragma unroll
  for (int r = 0; r < 4; ++r) linv[r] = 1.0f / lacc[r];   // no shuffles needed
#pragma unroll
  for (int jb = 0; jb < 4; ++jb) {
#pragma unroll
    for (int r = 0; r < 4; ++r) {
      const int row = q0 + wave * 16 + quad * 4 + r;
      attnb[(size_t)(b * S + row) * INNER + h * HD + jb * 16 + l16] =
          (_Float16)(o16[jb][r] * linv[r]);
    }
  }
}

// ---------------------------------------------------------------------------
extern "C" void kernel_launch(void* const* d_in, const int* in_sizes, int n_in,
                              void* d_out, int out_size, void* d_ws, size_t ws_size,
                              hipStream_t stream) {
  const float* hs    = (const float*)d_in[0];
  const float* rot   = (const float*)d_in[1];
  const float* w_qkv = (const float*)d_in[2];
  const float* b_qkv = (const float*)d_in[3];
  const float* nqw   = (const float*)d_in[4];
  const float* nkw   = (const float*)d_in[5];
  const float* w_out = (const float*)d_in[6];
  const float* b_out = (const float*)d_in[7];
  const float* hks   = (const float*)d_in[8];
  const int*   octx  = (const int*)d_in[9];

  _Float16* hsb   = (_Float16*)d_ws;                 // 0-8 MiB (attnb aliases)
  _Float16* attnb = hsb;
  _Float16* wqkvT = hsb   + (size_t)NTOK * DIM;      // 8-14 MiB
  _Float16* woutT = wqkvT + (size_t)QKVN * DIM;      // 14-16 MiB
  _Float16* qkvh  = woutT + (size_t)DIM * INNER;     // 16-40 MiB
  _Float16* q_h   = qkvh  + (size_t)NTOK * QKVN;     // 40-48 MiB
  _Float16* k_h   = q_h   + (size_t)B * NH * S * HD; // 48-56 MiB
  _Float16* vT    = k_h   + (size_t)B * NH * S * HD; // 56-64 MiB

  prep_all<<<3072, 256, 0, stream>>>(hs, w_qkv, w_out, hsb, wqkvT, woutT);

  gemm_bt<128, true, _Float16><<<dim3(QKVN / 128, NTOK / 128), 256, 0, stream>>>(
      hsb, wqkvT, b_qkv, qkvh, QKVN, DIM);

  post_all<<<5120, 256, 0, stream>>>(qkvh, rot, nqw, nkw, hks, octx, q_h, k_h, vT);

  attn_mfma<<<dim3(B * NH, S / 128), 512, 0, stream>>>(q_h, k_h, vT, attnb);

  gemm_bt<128, false, float><<<dim3(DIM / 128, NTOK / 128), 256, 0, stream>>>(
      attnb, woutT, b_out, (float*)d_out, DIM, INNER);
}

// Round 10
// 201.534 us; speedup vs baseline: 1.0983x; 1.0129x over previous
//
#include <hip/hip_runtime.h>
#include <math.h>

typedef float    floatx4 __attribute__((ext_vector_type(4)));
typedef _Float16 half8   __attribute__((ext_vector_type(8)));
typedef _Float16 half4v  __attribute__((ext_vector_type(4)));
typedef _Float16 half2v  __attribute__((ext_vector_type(2)));
typedef __fp16   fp16x2  __attribute__((ext_vector_type(2)));

constexpr int B    = 2;
constexpr int S    = 2048;
constexpr int NH   = 16;
constexpr int HD   = 64;
constexpr int DIM  = 1024;
constexpr int INNER = 1024;
constexpr int QKVN = 3072;
constexpr int NTOK = 4096;
constexpr float EPS = 1e-5f;
constexpr float MAX_SCALE = 10.0f;
constexpr float SCALE_LOG2E = 0.125f * 1.4426950408889634f;

#define MFMA32(a, b, c) __builtin_amdgcn_mfma_f32_16x16x32_f16((a), (b), (c), 0, 0, 0)

__device__ __forceinline__ half2v pkrtz(float a, float b) {
  fp16x2 t = __builtin_amdgcn_cvt_pkrtz(a, b);
  return __builtin_bit_cast(half2v, t);
}
__device__ __forceinline__ half2v hmax2(half2v a, half2v b) {
  return __builtin_elementwise_max(a, b);
}

// Direct global->LDS DMA, 16 B per lane (attn staging only; all GEMM
// DMA-staging variants measured WORSE than reg-prefetch: R1 157, R2/3 158,
// R4 162, R6 159 vs R0 152 us non-attn. Do not re-introduce in GEMM.)
__device__ __forceinline__ void gl_lds16(const _Float16* g, _Float16* l) {
  __builtin_amdgcn_global_load_lds(
      (__attribute__((address_space(1))) void*)g,
      (__attribute__((address_space(3))) void*)l, 16, 0, 0);
}

// ---------------------------------------------------------------------------
// Fused prep: blockIdx [0,2048) fp32->fp16 convert of hs;
// [2048,2816) transpose w_qkv; [2816,3072) transpose w_out.
// ---------------------------------------------------------------------------
__device__ __forceinline__ void transpose_tile(const float* __restrict__ w,
                                               _Float16* __restrict__ wT,
                                               int K, int N, int k0, int n0,
                                               _Float16* T, int tid) {
#pragma unroll
  for (int i = 0; i < 4; ++i) {
    int id = tid + 256 * i;
    int r = id >> 4, c = id & 15;
    float4 v = *(const float4*)&w[(size_t)(k0 + r) * N + n0 + c * 4];
    half4v s; s[0] = (_Float16)v.x; s[1] = (_Float16)v.y;
    s[2] = (_Float16)v.z; s[3] = (_Float16)v.w;
    *(half4v*)&T[r * 72 + c * 4] = s;
  }
  __syncthreads();
#pragma unroll
  for (int i = 0; i < 2; ++i) {
    int id = tid + 256 * i;
    int n = id >> 3, cs = id & 7;
    half8 o;
#pragma unroll
    for (int jj = 0; jj < 8; ++jj) o[jj] = T[(cs * 8 + jj) * 72 + n];
    *(half8*)&wT[(size_t)(n0 + n) * K + k0 + cs * 8] = o;
  }
}

__global__ __launch_bounds__(256)
void prep_all(const float* __restrict__ hs, const float* __restrict__ w_qkv,
              const float* __restrict__ w_out, _Float16* __restrict__ hsb,
              _Float16* __restrict__ wqkvT, _Float16* __restrict__ woutT) {
  __shared__ _Float16 T[64 * 72];
  const int bx = blockIdx.x, tid = threadIdx.x;
  if (bx < 2048) {
    int id = bx * 256 + tid;
    const float4 a = ((const float4*)hs)[id * 2];
    const float4 b = ((const float4*)hs)[id * 2 + 1];
    half8 o;
    o[0] = (_Float16)a.x; o[1] = (_Float16)a.y; o[2] = (_Float16)a.z; o[3] = (_Float16)a.w;
    o[4] = (_Float16)b.x; o[5] = (_Float16)b.y; o[6] = (_Float16)b.z; o[7] = (_Float16)b.w;
    ((half8*)hsb)[id] = o;
  } else if (bx < 2816) {
    int id = bx - 2048;
    transpose_tile(w_qkv, wqkvT, DIM, QKVN, (id / 48) * 64, (id % 48) * 64, T, tid);
  } else {
    int id = bx - 2816;
    transpose_tile(w_out, woutT, INNER, DIM, (id / 16) * 64, (id % 16) * 64, T, tid);
  }
}

// ---------------------------------------------------------------------------
// fp16 MFMA GEMM, reg-prefetch staging (measured-best mechanism), BK=64.
// R10: FUSE_V — blocks covering the V third of qkv (n0 >= 2048) write their
// accumulators DIRECTLY to vT in the transposed/swizzled fragment layout
// (byte-identical to what post_all's V-pass produced):
//   lane holds acc[i][j][r] = V[token tw = quad*4 + i*16 + r][d = j*16+l16]
//   -> vT tile position d*64 + quad*16 + i*4 + r  (contiguous 32B per lane,j)
// This deletes a full 8 MB write + 8 MB read of qkvh's V third.
// ---------------------------------------------------------------------------
template<int BN, bool OUT_F16, bool FUSE_V, typename OutT>
__global__ __launch_bounds__(256)
void gemm_bt(const _Float16* __restrict__ A, const _Float16* __restrict__ BT,
             const float* __restrict__ bias, OutT* __restrict__ C, int N, int K,
             _Float16* __restrict__ vt) {
  constexpr int NJ  = BN / 32;            // col-frags per wave
  constexpr int NSB = BN / 32;            // B staging slots per thread
  __shared__ _Float16 As[128 * 72];
  __shared__ _Float16 Bs[BN * 72];
  const int tid = threadIdx.x;
  const int wave = tid >> 6, lane = tid & 63, quad = lane >> 4, l16 = lane & 15;
  const int wm = wave >> 1, wn = wave & 1;
  const int m0 = blockIdx.y * 128, n0 = blockIdx.x * BN;

  // staging: thread covers rows r0+32s, k-cols [c0, c0+8) of the 64-wide slice
  const int r0 = tid >> 3;                // 0..31
  const int c0 = (tid & 7) * 8;           // 0..56
  const _Float16* Ap = A  + (size_t)(m0 + r0) * K + c0;
  const _Float16* Bp = BT + (size_t)(n0 + r0) * K + c0;

  half8 ar[4], br[NSB];
#pragma unroll
  for (int s = 0; s < 4; ++s) ar[s] = *(const half8*)(Ap + (size_t)(32 * s) * K);
#pragma unroll
  for (int s = 0; s < NSB; ++s) br[s] = *(const half8*)(Bp + (size_t)(32 * s) * K);

  floatx4 acc[4][NJ] = {};

  for (int k0 = 0; k0 < K; k0 += 64) {
    __syncthreads();
#pragma unroll
    for (int s = 0; s < 4; ++s) *(half8*)&As[(r0 + 32 * s) * 72 + c0] = ar[s];
#pragma unroll
    for (int s = 0; s < NSB; ++s) *(half8*)&Bs[(r0 + 32 * s) * 72 + c0] = br[s];
    if (k0 + 64 < K) {
#pragma unroll
      for (int s = 0; s < 4; ++s)
        ar[s] = *(const half8*)(Ap + (size_t)(32 * s) * K + k0 + 64);
#pragma unroll
      for (int s = 0; s < NSB; ++s)
        br[s] = *(const half8*)(Bp + (size_t)(32 * s) * K + k0 + 64);
    }
    __syncthreads();
#pragma unroll
    for (int ks = 0; ks < 2; ++ks) {
      half8 a[4], b[NJ];
#pragma unroll
      for (int i = 0; i < 4; ++i)
        a[i] = *(const half8*)&As[(wm * 64 + i * 16 + l16) * 72 + ks * 32 + quad * 8];
#pragma unroll
      for (int j = 0; j < NJ; ++j)
        b[j] = *(const half8*)&Bs[(wn * (BN / 2) + j * 16 + l16) * 72 + ks * 32 + quad * 8];
#pragma unroll
      for (int i = 0; i < 4; ++i)
#pragma unroll
        for (int j = 0; j < NJ; ++j)
          acc[i][j] = MFMA32(a[i], b[j], acc[i][j]);
    }
  }

  const int rb = m0 + wm * 64 + quad * 4;
  const int cb = n0 + wn * (BN / 2) + l16;

  if constexpr (FUSE_V) {
    if (n0 >= 2 * INNER) {
      // V block: write vT directly (post_all layout), skip qkvh.
      const int h  = ((n0 - 2 * INNER) >> 6) + wn;     // head (one per wave)
      const int bb = m0 >> 11;                          // batch
      const int kt = ((m0 & (S - 1)) >> 6) + wm;        // 64-token tile idx
      _Float16* orow = vt + ((size_t)(bb * NH + h) * 32 + kt) * (64 * 64);
#pragma unroll
      for (int j = 0; j < NJ; ++j) {
        const float bj = bias[cb + j * 16];
        const int d = j * 16 + l16;
#pragma unroll
        for (int i = 0; i < 4; ++i) {
          half4v o;
#pragma unroll
          for (int r = 0; r < 4; ++r) o[r] = (_Float16)(acc[i][j][r] + bj);
          *(half4v*)&orow[d * 64 + quad * 16 + i * 4] = o;
        }
      }
      return;
    }
  }

#pragma unroll
  for (int j = 0; j < NJ; ++j) {
    const float bj = bias[cb + j * 16];
#pragma unroll
    for (int i = 0; i < 4; ++i) {
#pragma unroll
      for (int r = 0; r < 4; ++r) {
        float v = acc[i][j][r] + bj;
        size_t idx = (size_t)(rb + i * 16 + r) * N + cb + j * 16;
        if constexpr (OUT_F16) C[idx] = (_Float16)v; else C[idx] = v;
      }
    }
  }
}

// ---------------------------------------------------------------------------
// Fused post (R10: V-transpose removed — now done in gemm1's epilogue):
// 4096 blocks, per-token RMSNorm + rotary + hist-scale on q,k only.
// ---------------------------------------------------------------------------
__global__ __launch_bounds__(256)
void post_all(const _Float16* __restrict__ qkvh, const float* __restrict__ rot,
              const float* __restrict__ nqw, const float* __restrict__ nkw,
              const float* __restrict__ hks, const int* __restrict__ octx,
              _Float16* __restrict__ qo_, _Float16* __restrict__ ko_) {
  __shared__ float red[8];
  const int tid = threadIdx.x;
  const int token = blockIdx.x;
  const int b = token >> 11, spos = token & (S - 1);
  const _Float16* qrow = qkvh + (size_t)token * QKVN;
  const _Float16* krow = qrow + INNER;
  const float* r = rot + (size_t)token * (2 * HD);

  const int e0 = tid * 4;
  half4v qs = *(const half4v*)(qrow + e0);
  half4v ks = *(const half4v*)(krow + e0);
  float q4[4], k4[4];
#pragma unroll
  for (int i = 0; i < 4; ++i) { q4[i] = (float)qs[i]; k4[i] = (float)ks[i]; }

  float sq = 0.f, sk = 0.f;
#pragma unroll
  for (int i = 0; i < 4; ++i) { sq += q4[i] * q4[i]; sk += k4[i] * k4[i]; }
#pragma unroll
  for (int msk = 1; msk < 64; msk <<= 1) {
    sq += __shfl_xor(sq, msk);
    sk += __shfl_xor(sk, msk);
  }
  const int wv = tid >> 6;
  if ((tid & 63) == 0) { red[wv] = sq; red[4 + wv] = sk; }
  __syncthreads();
  sq = red[0] + red[1] + red[2] + red[3];
  sk = red[4] + red[5] + red[6] + red[7];

  const float qinv = 1.0f / sqrtf(sq * (1.0f / INNER) + EPS);
  const float kinv = 1.0f / sqrtf(sk * (1.0f / INNER) + EPS);

#pragma unroll
  for (int i = 0; i < 4; ++i) {
    q4[i] = q4[i] * qinv * nqw[e0 + i];
    k4[i] = k4[i] * kinv * nkw[e0 + i];
  }

  const int h = e0 >> 6, d0 = e0 & (HD - 1);
  const float c0 = r[d0],     s0 = r[HD + d0 + 1];
  const float c1 = r[d0 + 2], s1 = r[HD + d0 + 3];

  float qo[4], ko[4];
  qo[0] = q4[0] * c0 - q4[1] * s0;
  qo[1] = q4[0] * s0 + q4[1] * c0;
  qo[2] = q4[2] * c1 - q4[3] * s1;
  qo[3] = q4[2] * s1 + q4[3] * c1;
  ko[0] = k4[0] * c0 - k4[1] * s0;
  ko[1] = k4[0] * s0 + k4[1] * c0;
  ko[2] = k4[2] * c1 - k4[3] * s1;
  ko[3] = k4[2] * s1 + k4[3] * c1;

  const int hist = S - octx[0];
  if (hist > 0 && spos < hist) {
    const float sig = 1.0f / (1.0f + expf(-hks[h]));
    const float sc = 1.0f + sig * (MAX_SCALE - 1.0f);
#pragma unroll
    for (int i = 0; i < 4; ++i) ko[i] *= sc;
  }

  half4v qo4, ko4;
#pragma unroll
  for (int i = 0; i < 4; ++i) {
    qo4[i] = (_Float16)(qo[i] * SCALE_LOG2E);
    ko4[i] = (_Float16)ko[i];
  }
  const size_t obase = ((size_t)(b * NH + h) * S + spos) * HD + d0;
  *(half4v*)(qo_ + obase) = qo4;
  *(half4v*)(ko_ + obase) = ko4;
}

// ---------------------------------------------------------------------------
// MFMA flash attention — R7 version verbatim (measured best: 50.8 us).
// 512 thr = 8 waves, 16 Q-rows/wave, 2 K-tiles per barrier with shared
// max-update, DMA staging with XOR source swizzle, defer-max, ones-MFMA
// row-sum, PV via 16x16x32, T5 setprio around MFMA clusters.
// ---------------------------------------------------------------------------
__global__ __launch_bounds__(512, 4)
void attn_mfma(const _Float16* __restrict__ qb, const _Float16* __restrict__ kb,
               const _Float16* __restrict__ vt, _Float16* __restrict__ attnb) {
  __shared__ _Float16 Kbuf[2][2][64 * 64];
  __shared__ _Float16 Vbuf[2][2][64 * 64];
  const int bh = blockIdx.x;
  const int b = bh >> 4, h = bh & 15;
  const int q0 = blockIdx.y * 128;
  const int tid = threadIdx.x;
  const int wave = tid >> 6, lane = tid & 63, quad = lane >> 4, l16 = lane & 15;
  const int rx = l16 & 7;

  const _Float16* qbh = qb + (size_t)bh * S * HD;
  const _Float16* kbh = kb + (size_t)bh * S * HD;
  const _Float16* vbh = vt + (size_t)bh * S * HD;

  half8 aq[2];
#pragma unroll
  for (int ks = 0; ks < 2; ++ks)
    aq[ks] = *(const half8*)&qbh[(size_t)(q0 + wave * 16 + l16) * HD + ks * 32 + quad * 8];

  const int srow = wave * 8 + (lane >> 3);
  const int soff = srow * 64 + (((lane & 7) ^ (srow & 7)) * 8);

  auto stage = [&](int p, int buf) {
    const _Float16* kt = kbh + (size_t)p * 8192;
    const _Float16* vp = vbh + (size_t)p * 8192;
    gl_lds16(kt + soff,        &Kbuf[buf][0][wave * 512]);
    gl_lds16(kt + 4096 + soff, &Kbuf[buf][1][wave * 512]);
    gl_lds16(vp + soff,        &Vbuf[buf][0][wave * 512]);
    gl_lds16(vp + 4096 + soff, &Vbuf[buf][1][wave * 512]);
  };

  stage(0, 0);
  __syncthreads();   // drains vmcnt(0): pair 0 resident

  floatx4 o16[4] = {};
  floatx4 lacc = {};                      // row-sums, same layout as o16 rows
  float mrow = -INFINITY;

  half8 ones8;
#pragma unroll
  for (int i = 0; i < 8; ++i) ones8[i] = (_Float16)1.f;

  auto compute_pair = [&](const _Float16* K0, const _Float16* K1,
                          const _Float16* V0, const _Float16* V1) {
    floatx4 scA[4] = {}, scB[4] = {};
    __builtin_amdgcn_s_setprio(1);
#pragma unroll
    for (int jj = 0; jj < 4; ++jj) {
#pragma unroll
      for (int ks = 0; ks < 2; ++ks) {
        const int co = (jj * 16 + l16) * 64 + (((ks * 4 + quad) ^ rx) * 8);
        half8 akA = *(const half8*)&K0[co];
        half8 akB = *(const half8*)&K1[co];
        scA[jj] = MFMA32(akA, aq[ks], scA[jj]);
        scB[jj] = MFMA32(akB, aq[ks], scB[jj]);
      }
    }
    __builtin_amdgcn_s_setprio(0);

    half2v phA[8], phB[8];
#pragma unroll
    for (int jj = 0; jj < 4; ++jj) {
      phA[jj * 2]     = pkrtz(scA[jj][0], scA[jj][1]);
      phA[jj * 2 + 1] = pkrtz(scA[jj][2], scA[jj][3]);
      phB[jj * 2]     = pkrtz(scB[jj][0], scB[jj][1]);
      phB[jj * 2 + 1] = pkrtz(scB[jj][2], scB[jj][3]);
    }
    half2v mA = hmax2(hmax2(hmax2(phA[0], phA[1]), hmax2(phA[2], phA[3])),
                      hmax2(hmax2(phA[4], phA[5]), hmax2(phA[6], phA[7])));
    half2v mB = hmax2(hmax2(hmax2(phB[0], phB[1]), hmax2(phB[2], phB[3])),
                      hmax2(hmax2(phB[4], phB[5]), hmax2(phB[6], phB[7])));
    half2v mx2 = hmax2(mA, mB);
    int mi = __builtin_bit_cast(int, mx2);
    mx2 = hmax2(mx2, __builtin_bit_cast(half2v, __shfl_xor(mi, 16)));
    mi = __builtin_bit_cast(int, mx2);
    mx2 = hmax2(mx2, __builtin_bit_cast(half2v, __shfl_xor(mi, 32)));
    const float mxf = fmaxf((float)mx2[0], (float)mx2[1]);
    const bool up = mxf > mrow + 4.0f;
    const float mn = up ? mxf : mrow;
    const float alpha = up ? exp2f(mrow - mn) : 1.0f;
    mrow = mn;

    const _Float16 mnh = (_Float16)mn;
    half2v mn2; mn2[0] = mnh; mn2[1] = mnh;
    half2v peA[8], peB[8];
#pragma unroll
    for (int i = 0; i < 8; ++i) {
      peA[i] = __builtin_elementwise_exp2(phA[i] - mn2);
      peB[i] = __builtin_elementwise_exp2(phB[i] - mn2);
    }

    if (__ballot(up)) {
      float alr[4];
#pragma unroll
      for (int r = 0; r < 4; ++r) alr[r] = __shfl(alpha, quad * 4 + r);
#pragma unroll
      for (int jb = 0; jb < 4; ++jb)
#pragma unroll
        for (int r = 0; r < 4; ++r) o16[jb][r] *= alr[r];
#pragma unroll
      for (int r = 0; r < 4; ++r) lacc[r] *= alr[r];
    }

    half8 pA[2], pB[2];
#pragma unroll
    for (int t = 0; t < 2; ++t) {
      half4v loA = __builtin_shufflevector(peA[4 * t],     peA[4 * t + 1], 0, 1, 2, 3);
      half4v hiA = __builtin_shufflevector(peA[4 * t + 2], peA[4 * t + 3], 0, 1, 2, 3);
      pA[t] = __builtin_shufflevector(loA, hiA, 0, 1, 2, 3, 4, 5, 6, 7);
      half4v loB = __builtin_shufflevector(peB[4 * t],     peB[4 * t + 1], 0, 1, 2, 3);
      half4v hiB = __builtin_shufflevector(peB[4 * t + 2], peB[4 * t + 3], 0, 1, 2, 3);
      pB[t] = __builtin_shufflevector(loB, hiB, 0, 1, 2, 3, 4, 5, 6, 7);
    }

    __builtin_amdgcn_s_setprio(1);
    lacc = MFMA32(pA[0], ones8, lacc);
    lacc = MFMA32(pA[1], ones8, lacc);
    lacc = MFMA32(pB[0], ones8, lacc);
    lacc = MFMA32(pB[1], ones8, lacc);

#pragma unroll
    for (int jb = 0; jb < 4; ++jb) {
      const int vrow = (jb * 16 + l16) * 64;
#pragma unroll
      for (int t = 0; t < 2; ++t) {
        half8 vA = *(const half8*)&V0[vrow + (((2 * quad + t) ^ rx) * 8)];
        half8 vB = *(const half8*)&V1[vrow + (((2 * quad + t) ^ rx) * 8)];
        o16[jb] = MFMA32(pA[t], vA, o16[jb]);
        o16[jb] = MFMA32(pB[t], vB, o16[jb]);
      }
    }
    __builtin_amdgcn_s_setprio(0);
  };

  int cur = 0;
  for (int p = 0; p < 16; ++p) {     // 16 pairs of 64-row K/V tiles
    if (p + 1 < 16) stage(p + 1, cur ^ 1);   // DMA; flies under compute
    compute_pair(Kbuf[cur][0], Kbuf[cur][1], Vbuf[cur][0], Vbuf[cur][1]);
    __syncthreads();                         // drains vmcnt: next pair ready
    cur ^= 1;
  }

  float linv[4];
#pragma unroll
  for (int r = 0; r < 4; ++r) linv[r] = 1.0f / lacc[r];   // no shuffles needed
#pragma unroll
  for (int jb = 0; jb < 4; ++jb) {
#pragma unroll
    for (int r = 0; r < 4; ++r) {
      const int row = q0 + wave * 16 + quad * 4 + r;
      attnb[(size_t)(b * S + row) * INNER + h * HD + jb * 16 + l16] =
          (_Float16)(o16[jb][r] * linv[r]);
    }
  }
}

// ---------------------------------------------------------------------------
extern "C" void kernel_launch(void* const* d_in, const int* in_sizes, int n_in,
                              void* d_out, int out_size, void* d_ws, size_t ws_size,
                              hipStream_t stream) {
  const float* hs    = (const float*)d_in[0];
  const float* rot   = (const float*)d_in[1];
  const float* w_qkv = (const float*)d_in[2];
  const float* b_qkv = (const float*)d_in[3];
  const float* nqw   = (const float*)d_in[4];
  const float* nkw   = (const float*)d_in[5];
  const float* w_out = (const float*)d_in[6];
  const float* b_out = (const float*)d_in[7];
  const float* hks   = (const float*)d_in[8];
  const int*   octx  = (const int*)d_in[9];

  _Float16* hsb   = (_Float16*)d_ws;                 // 0-8 MiB (attnb aliases)
  _Float16* attnb = hsb;
  _Float16* wqkvT = hsb   + (size_t)NTOK * DIM;      // 8-14 MiB
  _Float16* woutT = wqkvT + (size_t)QKVN * DIM;      // 14-16 MiB
  _Float16* qkvh  = woutT + (size_t)DIM * INNER;     // 16-40 MiB
  _Float16* q_h   = qkvh  + (size_t)NTOK * QKVN;     // 40-48 MiB
  _Float16* k_h   = q_h   + (size_t)B * NH * S * HD; // 48-56 MiB
  _Float16* vT    = k_h   + (size_t)B * NH * S * HD; // 56-64 MiB

  prep_all<<<3072, 256, 0, stream>>>(hs, w_qkv, w_out, hsb, wqkvT, woutT);

  gemm_bt<128, true, true, _Float16><<<dim3(QKVN / 128, NTOK / 128), 256, 0, stream>>>(
      hsb, wqkvT, b_qkv, qkvh, QKVN, DIM, vT);

  post_all<<<4096, 256, 0, stream>>>(qkvh, rot, nqw, nkw, hks, octx, q_h, k_h);

  attn_mfma<<<dim3(B * NH, S / 128), 512, 0, stream>>>(q_h, k_h, vT, attnb);

  gemm_bt<128, false, false, float><<<dim3(DIM / 128, NTOK / 128), 256, 0, stream>>>(
      attnb, woutT, b_out, (float*)d_out, DIM, INNER, nullptr);
}